// Round 2
// baseline (944.935 us; speedup 1.0000x reference)
//
#include <hip/hip_runtime.h>
#include <math.h>

// LSTM B=8192,T=512,IN=3,H=32,OUT=2 fp32 -> MFMA bf16 hi/lo (error ~2^-16).
// Block = 128 thr = 2 waves = 16 batches. D[row=gate,col=batch]:
//   A-frag = W_hh rows (constant, VGPR-resident), B-frag = h (per step).
// wave0: gate rows 0..63 (i,f); wave1: rows 64..127 (g,o).
// c/h update split per unit-half across waves; LDS exchange, 2 barriers/step.
// Weight rows pre-scaled by log2e (g-rows by 2*log2e) so v_exp_f32 is exp2.

namespace {
constexpr int   kT   = 512;
constexpr float kL2E = 1.44269504088896340736f;
}

typedef __bf16 bf16x8 __attribute__((ext_vector_type(8)));
typedef float  f32x4  __attribute__((ext_vector_type(4)));

union Frag {
    bf16x8 v;
    unsigned short u[8];
    uint2 d2[2];
    uint4 d4;
};

__device__ __forceinline__ unsigned short bf_rne(float f) {
    unsigned u = __float_as_uint(f);
    u += 0x7fffu + ((u >> 16) & 1u);
    return (unsigned short)(u >> 16);
}
__device__ __forceinline__ float bf_tof(unsigned short h) {
    return __uint_as_float((unsigned)h << 16);
}
#if __has_builtin(__builtin_amdgcn_exp2f)
__device__ __forceinline__ float fast_exp2(float v) { return __builtin_amdgcn_exp2f(v); }
#else
__device__ __forceinline__ float fast_exp2(float v) { return exp2f(v); }
#endif
__device__ __forceinline__ float fast_rcp(float v) { return __builtin_amdgcn_rcpf(v); }

#define MFMA16 __builtin_amdgcn_mfma_f32_16x16x32_bf16

extern "C" __global__ __launch_bounds__(128, 1)
void lstm_mfma(const float* __restrict__ x,
               const float* __restrict__ W_ih,
               const float* __restrict__ W_hh,
               const float* __restrict__ b_ih,
               const float* __restrict__ b_hh,
               const float* __restrict__ W_fc,
               const float* __restrict__ b_fc,
               float* __restrict__ out) {
    const int tid  = threadIdx.x;
    const int lane = tid & 63;
    const int wv   = tid >> 6;      // 0: rows 0..63 (i,f); 1: rows 64..127 (g,o)
    const int n    = lane & 15;     // batch col (B/D) or row-in-chunk (A)
    const int q    = lane >> 4;     // quad
    const int b    = blockIdx.x * 16 + n;

    // LDS: gate exchange (fp32, padded 36) and h hi/lo (bf16 bits, padded 40)
    __shared__ __align__(16) float          sg1[16][36];
    __shared__ __align__(16) float          sg2[16][36];
    __shared__ __align__(16) unsigned short shh[16][40];
    __shared__ __align__(16) unsigned short shl[16][40];

    // ---- preload A-frags (scaled weights, hi/lo) + bias C-init ----
    Frag  Ah[4], Al[4], AXh[4], AXl[4];
    f32x4 biasC[4];
#pragma unroll
    for (int cc = 0; cc < 4; ++cc) {
        const int   gc = wv * 4 + cc;                    // global chunk 0..7
        const float s  = ((gc >> 1) == 2) ? 2.0f * kL2E : kL2E;
        const int   ar = gc * 16 + n;                    // A-frag row
#pragma unroll
        for (int j = 0; j < 8; ++j) {
            float w = W_hh[ar * 32 + q * 8 + j] * s;
            unsigned short hb = bf_rne(w);
            Ah[cc].u[j] = hb;
            Al[cc].u[j] = bf_rne(w - bf_tof(hb));
            AXh[cc].u[j] = 0;
            AXl[cc].u[j] = 0;
        }
        if (q == 0) {
#pragma unroll
            for (int j = 0; j < 3; ++j) {
                float w = W_ih[ar * 3 + j] * s;
                unsigned short hb = bf_rne(w);
                AXh[cc].u[j] = hb;
                AXl[cc].u[j] = bf_rne(w - bf_tof(hb));
            }
        }
#pragma unroll
        for (int r = 0; r < 4; ++r) {
            const int row = gc * 16 + q * 4 + r;
            biasC[cc][r] = (b_ih[row] + b_hh[row]) * s;
        }
    }

    const float* xb = x + (size_t)b * kT * 3;

    Frag Bh, Bl, BXh, BXl;
#pragma unroll
    for (int j = 0; j < 8; ++j) { Bh.u[j] = 0; Bl.u[j] = 0; BXh.u[j] = 0; BXl.u[j] = 0; }
    {   // x fragment for t = 0
        float x0 = xb[0], x1 = xb[1], x2 = xb[2];
        if (q != 0) { x0 = 0.f; x1 = 0.f; x2 = 0.f; }
        unsigned short h0 = bf_rne(x0), h1 = bf_rne(x1), h2 = bf_rne(x2);
        BXh.u[0] = h0; BXh.u[1] = h1; BXh.u[2] = h2;
        BXl.u[0] = bf_rne(x0 - bf_tof(h0));
        BXl.u[1] = bf_rne(x1 - bf_tof(h1));
        BXl.u[2] = bf_rne(x2 - bf_tof(h2));
    }

    float cst[4] = {0.f, 0.f, 0.f, 0.f};     // my 4 cell states
    const int wc = wv;         // chunk-within-gate handed to the other wave
    const int kc = 1 - wv;     // chunk kept for my c-update
    const int uo = 16 * wv;    // LDS unit-offset of handed-off group
    const int uw = 16 - uo;    // LDS unit-offset of my kept group

    for (int t = 0; t < kT; ++t) {
        // ---- gates on the matrix pipe ----
        f32x4 acc[4];
#pragma unroll
        for (int cc = 0; cc < 4; ++cc) {
            f32x4 a = MFMA16(Ah[cc].v,  Bh.v,  biasC[cc], 0, 0, 0);
            a = MFMA16(Al[cc].v,  Bh.v,  a, 0, 0, 0);
            a = MFMA16(Ah[cc].v,  Bl.v,  a, 0, 0, 0);
            a = MFMA16(AXh[cc].v, BXh.v, a, 0, 0, 0);
            a = MFMA16(AXl[cc].v, BXh.v, a, 0, 0, 0);
            a = MFMA16(AXh[cc].v, BXl.v, a, 0, 0, 0);
            acc[cc] = a;
        }

        // prefetch next x early (latency hidden under nonlinearities)
        const int tn = (t + 1 < kT) ? t + 1 : t;
        const float xn0 = xb[tn * 3 + 0];
        const float xn1 = xb[tn * 3 + 1];
        const float xn2 = xb[tn * 3 + 2];

        // ---- nonlinearities (rows pre-scaled: exp2 direct) ----
        float tA[8], tB[8];
#pragma unroll
        for (int k2 = 0; k2 < 8; ++k2) {
            const float rawA = acc[(k2 >> 2)][k2 & 3];       // i or g
            const float rawB = acc[2 + (k2 >> 2)][k2 & 3];   // f or o
            const float sA = fast_rcp(1.0f + fast_exp2(-rawA));
            tA[k2] = (wv == 0) ? sA : fmaf(2.0f, sA, -1.0f); // sigma(i) | tanh(g)
            tB[k2] = fast_rcp(1.0f + fast_exp2(-rawB));      // sigma(f|o)
        }

        // ---- exchange handed-off gate pair ----
        *(float4*)&sg1[n][uo + 4 * q] =
            make_float4(tA[wc * 4 + 0], tA[wc * 4 + 1], tA[wc * 4 + 2], tA[wc * 4 + 3]);
        *(float4*)&sg2[n][uo + 4 * q] =
            make_float4(tB[wc * 4 + 0], tB[wc * 4 + 1], tB[wc * 4 + 2], tB[wc * 4 + 3]);
        __syncthreads();
        const float4 rA = *(const float4*)&sg1[n][uw + 4 * q];
        const float4 rB = *(const float4*)&sg2[n][uw + 4 * q];

        // ---- c/h update for my 4 units ----
        unsigned short hhi[4], hlo[4];
#pragma unroll
        for (int r = 0; r < 4; ++r) {
            const float kA = tA[kc * 4 + r];
            const float kB = tB[kc * 4 + r];
            const float rAv = (r == 0) ? rA.x : (r == 1) ? rA.y : (r == 2) ? rA.z : rA.w;
            const float rBv = (r == 0) ? rB.x : (r == 1) ? rB.y : (r == 2) ? rB.z : rB.w;
            const float iv = (wv == 0) ? kA : rAv;
            const float fv = (wv == 0) ? kB : rBv;
            const float gv = (wv == 0) ? rAv : kA;
            const float ov = (wv == 0) ? rBv : kB;
            float c = fmaf(fv, cst[r], iv * gv);
            cst[r] = c;
            const float e2 = fast_exp2(-(c * (2.0f * kL2E)));
            const float th = fmaf(2.0f, fast_rcp(1.0f + e2), -1.0f);
            const float hv = ov * th;
            hhi[r] = bf_rne(hv);
            hlo[r] = bf_rne(hv - bf_tof(hhi[r]));
        }
        *(uint2*)&shh[n][uw + 4 * q] =
            make_uint2((unsigned)hhi[0] | ((unsigned)hhi[1] << 16),
                       (unsigned)hhi[2] | ((unsigned)hhi[3] << 16));
        *(uint2*)&shl[n][uw + 4 * q] =
            make_uint2((unsigned)hlo[0] | ((unsigned)hlo[1] << 16),
                       (unsigned)hlo[2] | ((unsigned)hlo[3] << 16));
        __syncthreads();

        // ---- reload B-frags (h hi/lo) for next step ----
        Bh.d4 = *(const uint4*)&shh[n][8 * q];
        Bl.d4 = *(const uint4*)&shl[n][8 * q];

        // ---- build next x fragment ----
        float x0 = xn0, x1 = xn1, x2 = xn2;
        if (q != 0) { x0 = 0.f; x1 = 0.f; x2 = 0.f; }
        const unsigned short h0 = bf_rne(x0), h1 = bf_rne(x1), h2 = bf_rne(x2);
        BXh.u[0] = h0; BXh.u[1] = h1; BXh.u[2] = h2;
        BXl.u[0] = bf_rne(x0 - bf_tof(h0));
        BXl.u[1] = bf_rne(x1 - bf_tof(h1));
        BXl.u[2] = bf_rne(x2 - bf_tof(h2));
    }

    // ---- epilogue: out[b][o] = h . W_fc[o] + b_fc[o] (B-frags hold h(T-1)) ----
    if (wv == 0) {
        float s0 = 0.f, s1 = 0.f;
#pragma unroll
        for (int j = 0; j < 8; ++j) {
            const float hj = bf_tof(Bh.u[j]) + bf_tof(Bl.u[j]);
            s0 = fmaf(hj, W_fc[8 * q + j], s0);
            s1 = fmaf(hj, W_fc[32 + 8 * q + j], s1);
        }
        s0 += __shfl_xor(s0, 16); s0 += __shfl_xor(s0, 32);
        s1 += __shfl_xor(s1, 16); s1 += __shfl_xor(s1, 32);
        if (q == 0) {
            out[(size_t)b * 2 + 0] = s0 + b_fc[0];
            out[(size_t)b * 2 + 1] = s1 + b_fc[1];
        }
    }
}

extern "C" void kernel_launch(void* const* d_in, const int* in_sizes, int n_in,
                              void* d_out, int out_size, void* d_ws, size_t ws_size,
                              hipStream_t stream) {
    const float* x    = (const float*)d_in[0];
    const float* W_ih = (const float*)d_in[1];
    const float* W_hh = (const float*)d_in[2];
    const float* b_ih = (const float*)d_in[3];
    const float* b_hh = (const float*)d_in[4];
    const float* W_fc = (const float*)d_in[5];
    const float* b_fc = (const float*)d_in[6];
    float* out = (float*)d_out;

    const int batch = in_sizes[0] / (kT * 3);   // 8192
    dim3 grid(batch / 16);                      // 512 blocks
    dim3 block(128);                            // 2 waves
    hipLaunchKernelGGL(lstm_mfma, grid, block, 0, stream,
                       x, W_ih, W_hh, b_ih, b_hh, W_fc, b_fc, out);
}

// Round 3
// 513.574 us; speedup vs baseline: 1.8399x; 1.8399x over previous
//
#include <hip/hip_runtime.h>
#include <math.h>

// LSTM B=8192,T=512,IN=3,H=32,OUT=2 fp32.
// One wave owns 16 batches end-to-end. A = permuted W_hh rows (VGPR-resident,
// bf16 hi/lo), B = h (bf16 hi/lo). Row permutation puts gates i,f,g,o of units
// 8q..8q+7 into lane (n,q)'s D regs -> c/h update is lane-local and h lands
// exactly in that lane's B-frag slots for the next step. Zero LDS, zero
// barriers, zero shuffles in the T-loop. x@W_ih + bias folded into one MFMA
// per chunk via K-packing. Rows pre-scaled by -log2e (-2log2e for g) so all
// nonlinearities are raw v_exp_f32 + v_rcp_f32 (8 trans/unit via rcp sharing).

namespace {
constexpr int   kT   = 512;
constexpr float kL2E = 1.44269504088896340736f;
}

typedef __bf16 bf16x8 __attribute__((ext_vector_type(8)));
typedef float  f32x4  __attribute__((ext_vector_type(4)));

union Frag {
    bf16x8 v;
    unsigned short u[8];
};

__device__ __forceinline__ unsigned short bf_rne(float f) {
    unsigned u = __float_as_uint(f);
    u += 0x7fffu + ((u >> 16) & 1u);
    return (unsigned short)(u >> 16);
}
__device__ __forceinline__ float bf_tof(unsigned short h) {
    return __uint_as_float((unsigned)h << 16);
}
__device__ __forceinline__ float fast_exp2(float v) { return __builtin_amdgcn_exp2f(v); }
__device__ __forceinline__ float fast_rcp(float v)  { return __builtin_amdgcn_rcpf(v); }

#define MFMA16 __builtin_amdgcn_mfma_f32_16x16x32_bf16

extern "C" __global__ __launch_bounds__(64, 1)
void lstm_solo(const float* __restrict__ x,
               const float* __restrict__ W_ih,
               const float* __restrict__ W_hh,
               const float* __restrict__ b_ih,
               const float* __restrict__ b_hh,
               const float* __restrict__ W_fc,
               const float* __restrict__ b_fc,
               float* __restrict__ out) {
    const int lane = threadIdx.x & 63;
    const int n    = lane & 15;     // batch col (B/D) == A-frag row m
    const int q    = lane >> 4;     // quad: k-group for A/B, row-group for D
    const int b    = blockIdx.x * 16 + n;

    // ---- prologue: load permuted, scaled A-frags (hi/lo) ----
    Frag Ah[8], Al[8], AX[8];
#pragma unroll
    for (int cc = 0; cc < 8; ++cc) {
        const int   g = cc >> 1, p = cc & 1;
        const float s = (g == 2) ? -2.0f * kL2E : -kL2E;
        // A row m = n of chunk cc holds W row R:
        const int R = 32 * g + 8 * (n >> 2) + 4 * p + (n & 3);
#pragma unroll
        for (int j = 0; j < 8; ++j) {
            const float w = W_hh[R * 32 + 8 * q + j] * s;
            const unsigned short hb = bf_rne(w);
            Ah[cc].u[j] = hb;
            Al[cc].u[j] = bf_rne(w - bf_tof(hb));
        }
        // AX: k0-2 Wih_hi, k3-5 Wih_lo, k6-8 Wih_hi, k9 bias_hi, k10 bias_lo
        float wh[3], wl[3];
#pragma unroll
        for (int j = 0; j < 3; ++j) {
            const float w = W_ih[R * 3 + j] * s;
            const unsigned short hb = bf_rne(w);
            wh[j] = bf_tof(hb);
            wl[j] = w - wh[j];
        }
        const float bias = (b_ih[R] + b_hh[R]) * s;
        const unsigned short bh = bf_rne(bias);
#pragma unroll
        for (int j = 0; j < 8; ++j) AX[cc].u[j] = 0;
        if (q == 0) {
            AX[cc].u[0] = bf_rne(wh[0]); AX[cc].u[1] = bf_rne(wh[1]); AX[cc].u[2] = bf_rne(wh[2]);
            AX[cc].u[3] = bf_rne(wl[0]); AX[cc].u[4] = bf_rne(wl[1]); AX[cc].u[5] = bf_rne(wl[2]);
            AX[cc].u[6] = bf_rne(wh[0]); AX[cc].u[7] = bf_rne(wh[1]);
        } else if (q == 1) {
            AX[cc].u[0] = bf_rne(wh[2]);
            AX[cc].u[1] = bh;
            AX[cc].u[2] = bf_rne(bias - bf_tof(bh));
        }
    }

    const float* xb = x + (size_t)b * kT * 3;

    // ---- state ----
    float cst[8];
#pragma unroll
    for (int ul = 0; ul < 8; ++ul) cst[ul] = 0.0f;
    Frag Bh, Bl, BX;
#pragma unroll
    for (int j = 0; j < 8; ++j) { Bh.u[j] = 0; Bl.u[j] = 0; }

    const bool q0 = (q == 0);
    const bool q1 = (q == 1);
    const unsigned short ONE = 0x3F80;

    // build BX from x(t=0)
    {
        const float x0 = xb[0], x1 = xb[1], x2 = xb[2];
        const unsigned short xh0 = bf_rne(x0), xh1 = bf_rne(x1), xh2 = bf_rne(x2);
        const unsigned short xl0 = bf_rne(x0 - bf_tof(xh0));
        const unsigned short xl1 = bf_rne(x1 - bf_tof(xh1));
        const unsigned short xl2 = bf_rne(x2 - bf_tof(xh2));
        BX.u[0] = q0 ? xh0 : (q1 ? xl2 : (unsigned short)0);
        BX.u[1] = q0 ? xh1 : (q1 ? ONE : (unsigned short)0);
        BX.u[2] = q0 ? xh2 : (q1 ? ONE : (unsigned short)0);
        BX.u[3] = q0 ? xh0 : (unsigned short)0;
        BX.u[4] = q0 ? xh1 : (unsigned short)0;
        BX.u[5] = q0 ? xh2 : (unsigned short)0;
        BX.u[6] = q0 ? xl0 : (unsigned short)0;
        BX.u[7] = q0 ? xl1 : (unsigned short)0;
    }

    for (int t = 0; t < kT; ++t) {
        // ---- gates on the matrix pipe: acc[cc] = W_x.x + bias + W_hh.h ----
        const f32x4 z = {0.f, 0.f, 0.f, 0.f};
        f32x4 acc[8];
#pragma unroll
        for (int cc = 0; cc < 8; ++cc) acc[cc] = MFMA16(AX[cc].v, BX.v, z, 0, 0, 0);
#pragma unroll
        for (int cc = 0; cc < 8; ++cc) acc[cc] = MFMA16(Ah[cc].v, Bh.v, acc[cc], 0, 0, 0);
#pragma unroll
        for (int cc = 0; cc < 8; ++cc) acc[cc] = MFMA16(Al[cc].v, Bh.v, acc[cc], 0, 0, 0);
#pragma unroll
        for (int cc = 0; cc < 8; ++cc) acc[cc] = MFMA16(Ah[cc].v, Bl.v, acc[cc], 0, 0, 0);

        // prefetch next x while MFMAs drain
        const int tn = (t + 1 < kT) ? t + 1 : t;
        const float xn0 = xb[tn * 3 + 0];
        const float xn1 = xb[tn * 3 + 1];
        const float xn2 = xb[tn * 3 + 2];

        // ---- lane-local c/h update for units 8q..8q+7 ----
        // acc value = -l2e * preact (i,f,o) or -2*l2e * preact (g)
        // => E = exp2(acc) = e^{-preact} (or e^{-2 preact})
#pragma unroll
        for (int ul = 0; ul < 8; ++ul) {
            const int p = ul >> 2, r = ul & 3;
            const float Ei = fast_exp2(acc[0 + p][r]);
            const float Ef = fast_exp2(acc[2 + p][r]);
            float       Eg = fast_exp2(acc[4 + p][r]);
            const float Eo = fast_exp2(acc[6 + p][r]);
            Eg = fminf(Eg, 1e30f);
            const float sf  = fast_rcp(1.0f + Ef);                    // sigma(f)
            const float dig = fast_rcp((1.0f + Ei) * (1.0f + Eg));
            const float ig  = (1.0f - Eg) * dig;                      // sigma(i)*tanh(g)
            const float c   = fmaf(sf, cst[ul], ig);
            cst[ul] = c;
            float Ec = fast_exp2(c * (-2.0f * kL2E));
            Ec = fminf(Ec, 1e30f);
            const float doc = fast_rcp((1.0f + Eo) * (1.0f + Ec));
            const float h   = (1.0f - Ec) * doc;                      // sigma(o)*tanh(c)
            const unsigned short hh = bf_rne(h);
            Bh.u[ul] = hh;
            Bl.u[ul] = bf_rne(h - bf_tof(hh));
        }

        // ---- build BX for next step ----
        const unsigned short xh0 = bf_rne(xn0), xh1 = bf_rne(xn1), xh2 = bf_rne(xn2);
        const unsigned short xl0 = bf_rne(xn0 - bf_tof(xh0));
        const unsigned short xl1 = bf_rne(xn1 - bf_tof(xh1));
        const unsigned short xl2 = bf_rne(xn2 - bf_tof(xh2));
        BX.u[0] = q0 ? xh0 : (q1 ? xl2 : (unsigned short)0);
        BX.u[1] = q0 ? xh1 : (q1 ? ONE : (unsigned short)0);
        BX.u[2] = q0 ? xh2 : (q1 ? ONE : (unsigned short)0);
        BX.u[3] = q0 ? xh0 : (unsigned short)0;
        BX.u[4] = q0 ? xh1 : (unsigned short)0;
        BX.u[5] = q0 ? xh2 : (unsigned short)0;
        BX.u[6] = q0 ? xl0 : (unsigned short)0;
        BX.u[7] = q0 ? xl1 : (unsigned short)0;
    }

    // ---- epilogue: out[b][o] = sum_u h_u W_fc[o][u] + b_fc[o] ----
    // lane (n,q) holds h units 8q..8q+7 as Bh+Bl
    float s0 = 0.f, s1 = 0.f;
#pragma unroll
    for (int ul = 0; ul < 8; ++ul) {
        const float hj = bf_tof(Bh.u[ul]) + bf_tof(Bl.u[ul]);
        s0 = fmaf(hj, W_fc[8 * q + ul], s0);
        s1 = fmaf(hj, W_fc[32 + 8 * q + ul], s1);
    }
    s0 += __shfl_xor(s0, 16, 64); s0 += __shfl_xor(s0, 32, 64);
    s1 += __shfl_xor(s1, 16, 64); s1 += __shfl_xor(s1, 32, 64);
    if (q == 0) {
        out[(size_t)b * 2 + 0] = s0 + b_fc[0];
        out[(size_t)b * 2 + 1] = s1 + b_fc[1];
    }
}

extern "C" void kernel_launch(void* const* d_in, const int* in_sizes, int n_in,
                              void* d_out, int out_size, void* d_ws, size_t ws_size,
                              hipStream_t stream) {
    const float* x    = (const float*)d_in[0];
    const float* W_ih = (const float*)d_in[1];
    const float* W_hh = (const float*)d_in[2];
    const float* b_ih = (const float*)d_in[3];
    const float* b_hh = (const float*)d_in[4];
    const float* W_fc = (const float*)d_in[5];
    const float* b_fc = (const float*)d_in[6];
    float* out = (float*)d_out;

    const int batch = in_sizes[0] / (kT * 3);   // 8192
    dim3 grid(batch / 16);                      // 512 blocks, 1 wave each
    dim3 block(64);
    hipLaunchKernelGGL(lstm_solo, grid, block, 0, stream,
                       x, W_ih, W_hh, b_ih, b_hh, W_fc, b_fc, out);
}